// Round 4
// baseline (105.245 us; speedup 1.0000x reference)
//
#include <hip/hip_runtime.h>
#include <cstdint>

// PillarVFE fused (f32 in / f32 out), MI355X gfx950.
//
// Inputs: 0 voxels [P][32][4] f32 | 1 W [64][9] | 2 gamma [64] | 3 beta [64]
//         4 running_mean [64] | 5 running_var [64] | 6 voxel_num_points [P] i32
//         7 voxel_coords [P][4] i32.  Output: [P][64] f32.
//
// bn(conv(feats))[o] is affine in the raw point (v0,v1,v2,v3):
//   acc_n = v0*A0 + v1*A1 + v2*A2 + v3*A3 + C0 - cx*SW07 - cy*SW18 - meanterm
// meanterm is constant over n -> subtracted AFTER the max (exact).
// Masked rows (n>=npts) evaluate to C0 exactly -> folded in via fmaxf.
//
// Structure: setup kernel folds conv+BN into 10 per-channel constants in d_ws
// ([10][64], coalesced). Main kernel: 4 pillars/block, 1 wave per pillar
// (lane=channel). Staging waves (tid<128) also shuffle-reduce the per-pillar
// xyz sums from the registers they already hold, so compute waves never run
// the butterfly (was ~108 serial cycles per wave).

__global__ __launch_bounds__(64) void pillar_setup_kernel(
    const float* __restrict__ Wp,      // [64][9]
    const float* __restrict__ gamma_p,
    const float* __restrict__ beta_p,
    const float* __restrict__ rmean_p,
    const float* __restrict__ rvar_p,
    float*       __restrict__ params)  // [10][64]
{
    const int o = threadIdx.x;         // channel 0..63
    float w[9];
    #pragma unroll
    for (int c = 0; c < 9; ++c) w[c] = Wp[o * 9 + c];
    const float s = gamma_p[o] / sqrtf(rvar_p[o] + 1e-3f);

    params[0 * 64 + o] = (w[0] + w[4] + w[7]) * s;   // A0
    params[1 * 64 + o] = (w[1] + w[5] + w[8]) * s;   // A1
    params[2 * 64 + o] = (w[2] + w[6]) * s;          // A2
    params[3 * 64 + o] = w[3] * s;                   // A3
    params[4 * 64 + o] = beta_p[o] - rmean_p[o] * s; // C0
    params[5 * 64 + o] = (w[0] + w[7]) * s;          // SW07 (cx coeff)
    params[6 * 64 + o] = (w[1] + w[8]) * s;          // SW18 (cy coeff)
    params[7 * 64 + o] = w[4] * s;                   // SW4 (mx coeff)
    params[8 * 64 + o] = w[5] * s;                   // SW5 (my coeff)
    params[9 * 64 + o] = w[6] * s;                   // SW6 (mz coeff)
}

__global__ __launch_bounds__(256) void pillar_vfe_kernel(
    const float4* __restrict__ voxels4,   // [P*32] float4
    const float*  __restrict__ params,    // [10][64]
    const int*    __restrict__ npts_p,    // [P]
    const int4*   __restrict__ coords4,   // [P] int4
    float*        __restrict__ out,       // [P][64]
    int P)
{
    __shared__ float4 sh[4 * 32];         // 4 pillars x 32 points (AoS)
    __shared__ float4 sums4[4];           // per-pillar xyz sums

    const int tid    = threadIdx.x;
    const int pblock = blockIdx.x * 4;
    const int wave   = tid >> 6;
    const int lane   = tid & 63;

    // --- stage + per-pillar sum (waves 0,1 only) ---
    if (tid < 128) {
        const int pp   = tid >> 5;        // pillar-in-block 0..3
        const int t    = tid & 31;        // point index
        const int gidx = (pblock + pp) * 32 + t;
        float4 v = make_float4(0.f, 0.f, 0.f, 0.f);
        if (gidx < P * 32) v = voxels4[gidx];
        sh[tid] = v;
        // butterfly within each 32-lane half (xor masks < 32 stay in-half)
        float sx = v.x, sy = v.y, sz = v.z;
        #pragma unroll
        for (int m = 16; m >= 1; m >>= 1) {
            sx += __shfl_xor(sx, m, 64);
            sy += __shfl_xor(sy, m, 64);
            sz += __shfl_xor(sz, m, 64);
        }
        if ((lane & 31) == 0) sums4[pp] = make_float4(sx, sy, sz, 0.f);
    }
    __syncthreads();

    const int p = pblock + wave;
    if (p >= P) return;

    // per-channel folded constants (coalesced, L1/L2-resident)
    const float A0   = params[0 * 64 + lane];
    const float A1   = params[1 * 64 + lane];
    const float A2   = params[2 * 64 + lane];
    const float A3   = params[3 * 64 + lane];
    const float C0   = params[4 * 64 + lane];
    const float SW07 = params[5 * 64 + lane];
    const float SW18 = params[6 * 64 + lane];
    const float SW4  = params[7 * 64 + lane];
    const float SW5  = params[8 * 64 + lane];
    const float SW6  = params[9 * 64 + lane];

    const int   npts = npts_p[p];
    const int4  c4   = coords4[p];
    const float cx   = (float)c4.w * 0.16f + 0.08f;
    const float cy   = (float)c4.z * 0.16f + (0.08f - 39.68f);
    const float4 s4  = sums4[wave];

    const float C1 = C0 - cx * SW07 - cy * SW18;
    const float4* shp = sh + wave * 32;

    float vmax = -3.4e38f;
    #pragma unroll 4
    for (int n = 0; n < npts; ++n) {
        const float4 v = shp[n];          // same-addr broadcast, conflict-free
        float acc = C1;
        acc  = fmaf(v.x, A0, acc);
        acc  = fmaf(v.y, A1, acc);
        acc  = fmaf(v.z, A2, acc);
        acc  = fmaf(v.w, A3, acc);
        vmax = fmaxf(vmax, acc);
    }

    const float meanterm = (s4.x * SW4 + s4.y * SW5 + s4.z * SW6) / (float)npts;
    vmax -= meanterm;
    if (npts < 32) vmax = fmaxf(vmax, C0);   // masked rows contribute C0
    out[p * 64 + lane] = fmaxf(vmax, 0.0f);  // relu(max) == max(relu), nonempty
}

extern "C" void kernel_launch(void* const* d_in, const int* in_sizes, int n_in,
                              void* d_out, int out_size, void* d_ws, size_t ws_size,
                              hipStream_t stream) {
    const float4* voxels = (const float4*)d_in[0];
    const float*  W      = (const float*)d_in[1];
    const float*  gamma_ = (const float*)d_in[2];
    const float*  beta_  = (const float*)d_in[3];
    const float*  rmean  = (const float*)d_in[4];
    const float*  rvar   = (const float*)d_in[5];
    const int*    npts   = (const int*)d_in[6];
    const int4*   coords = (const int4*)d_in[7];
    float*        out    = (float*)d_out;
    float*        params = (float*)d_ws;     // 640 floats

    const int P = in_sizes[6];               // 40000

    pillar_setup_kernel<<<1, 64, 0, stream>>>(W, gamma_, beta_, rmean, rvar, params);

    const int blocks = (P + 3) / 4;          // 4 pillars / block (1 wave each)
    pillar_vfe_kernel<<<blocks, 256, 0, stream>>>(voxels, params, npts, coords, out, P);
}